// Round 1
// 375.142 us; speedup vs baseline: 1.0356x; 1.0356x over previous
//
#include <hip/hip_runtime.h>

// ---------------------------------------------------------------------------
// localTransformer: attention is dead code (softmax over singleton axis == 1,
// so o == v). Whole net folds to:
//   OUT = Wd0@X0 + Wd2p@gelu(A12@gelu(A1@X0 + b1p) + b12p) + bdp
// R3 restructure: single live accumulator via K=512 final GEMM
//   OUT = [Wd0 | Wd2p] @ [X0; H2]   (same accumulation order as before)
// R4 (this round): latency-bound fix.
//   (a) a-frag / b-frag register double-buffer (1 kt ahead) in gemm8 and G3 —
//       the 48-VGPR build had zero loads in flight, exposing ~200-300cy L2
//       latency per kt step on the 512KB/block weight stream.
//   (b) v_cvt_pk_bf16_f32 replaces manual integer RNE packing in staging and
//       both epilogues (~-500 VALU instr/thread).
// PIX=32/block, LDS 32KB swizzled, launch_bounds(256,4).
// ---------------------------------------------------------------------------

typedef short v8s __attribute__((ext_vector_type(8)));   // 8 bf16 (4 VGPRs)
typedef float v4f __attribute__((ext_vector_type(4)));   // MFMA C/D, float4

#define L_   16384        // H*W
#define PIX  32           // pixels per block

__device__ __forceinline__ unsigned short bf16rne(float f) {
  union { float f; unsigned u; } v; v.f = f;
  unsigned u = v.u;
  return (unsigned short)((u + 0x7FFFu + ((u >> 16) & 1u)) >> 16);
}

// packed f32x2 -> bf16x2 (RNE), one VALU instruction. low16 = lo, high16 = hi.
__device__ __forceinline__ unsigned cvt_pk_bf16(float lo, float hi) {
  unsigned r;
  asm("v_cvt_pk_bf16_f32 %0, %1, %2" : "=v"(r) : "v"(lo), "v"(hi));
  return r;
}

// tanh-form gelu, branchless (v_exp_f32). |err vs exact erf-gelu| <= ~3e-4,
// amplified downstream by <=1e-3 total -- threshold headroom is 0.06.
__device__ __forceinline__ float gelu_fast(float x) {
  float y = 1.5957691216057308f * (x + 0.044715f * x * x * x);  // 2*0.79788456*(...)
  float e = __expf(y);
  float t = 1.0f - 2.0f / (e + 1.0f);                           // tanh(y/2*2)=tanh
  return 0.5f * x * (1.0f + t);
}

// ---------------- prep: fold + bf16-pack weights ----------------
// A-frag pack order (NKT k-tiles): idx = ((mt*NKT + kt)*64 + lane)*8 + j
//   -> element A[mt*16 + (lane&15)][kt*32 + (lane>>4)*8 + j]

// 4 segments of 65536 threads:
//  seg0: pG3[:, :256]  = pack(Wd[:, :256])              (NKT=16, kt 0..7)
//  seg1: pG3[:, 256:]  = pack(fold(Wd[:,256:], W2))     (NKT=16, kt 8..15)
//  seg2: pA1           = pack(fold(W1, Wv))             (NKT=8)
//  seg3: T[g][cp][jj][c] = sum_j2 Wv[(g*16+cp)][j2*16+c] * W2[jj*16+j2]
__global__ void prep_pack_k(const float* __restrict__ Wv, const float* __restrict__ W1,
                            const float* __restrict__ W2, const float* __restrict__ Wd,
                            unsigned short* __restrict__ pA1, unsigned short* __restrict__ pG3,
                            float* __restrict__ T) {
  int gtid = blockIdx.x * 256 + threadIdx.x;
  int seg = gtid >> 16;
  int tid = gtid & 65535;
  if (seg == 3) {
    int c = tid & 15, jj = (tid >> 4) & 15, cp = (tid >> 8) & 15, g = tid >> 12;
    float s = 0.f;
    for (int j2 = 0; j2 < 16; ++j2)
      s += Wv[(g * 16 + cp) * 256 + j2 * 16 + c] * W2[jj * 16 + j2];
    T[tid] = s;
    return;
  }
  int j = tid & 7, lane = (tid >> 3) & 63, kt = (tid >> 9) & 7, mt = tid >> 12;
  int m = mt * 16 + (lane & 15);
  int k = kt * 32 + (lane >> 4) * 8 + j;
  if (seg == 0) {
    pG3[((mt * 16 + kt) * 64 + lane) * 8 + j] = bf16rne(Wd[m * 512 + k]);
  } else if (seg == 1) {
    int jj = k >> 4, c = k & 15;
    float s = 0.f;
    for (int j2 = 0; j2 < 16; ++j2)
      s += Wd[m * 512 + 256 + j2 * 16 + c] * W2[jj * 16 + j2];
    pG3[((mt * 16 + 8 + kt) * 64 + lane) * 8 + j] = bf16rne(s);
  } else {
    int jp = m >> 4, c = m & 15;
    float s = 0.f;
    for (int g = 0; g < 16; ++g) s += W1[g * 16 + jp] * Wv[(g * 16 + c) * 256 + k];
    pA1[tid] = bf16rne(s);
  }
}

// pA12 = pack(sum_g W1 * T)  -- same summation order as 1-stage fold.
__global__ void prep_a12_k(const float* __restrict__ W1, const float* __restrict__ T,
                           unsigned short* __restrict__ dst) {
  int tid = blockIdx.x * 256 + threadIdx.x;
  int j = tid & 7, lane = (tid >> 3) & 63, kt = (tid >> 9) & 7, mt = tid >> 12;
  int m = mt * 16 + (lane & 15);
  int k = kt * 32 + (lane >> 4) * 8 + j;
  int jp = m >> 4, cp = m & 15;
  int jj = k >> 4, c = k & 15;
  float s = 0.f;
  for (int g = 0; g < 16; ++g)
    s += W1[g * 16 + jp] * T[g * 4096 + cp * 256 + jj * 16 + c];
  dst[tid] = bf16rne(s);
}

__global__ void prep_bias_k(const float* __restrict__ Wv, const float* __restrict__ bv,
                            const float* __restrict__ Wd, const float* __restrict__ W1,
                            const float* __restrict__ b1, const float* __restrict__ b2,
                            const float* __restrict__ bd,
                            float* __restrict__ b1p, float* __restrict__ b12p,
                            float* __restrict__ bdp) {
  __shared__ float tmp[256];
  int h = threadIdx.x;
  {
    int g = h >> 4, cp = h & 15;
    float s = bv[g * 16 + cp];
    for (int j2 = 0; j2 < 16; ++j2) {
      float b2v = b2[j2];
      for (int c = 0; c < 16; ++c) s += Wv[(g * 16 + cp) * 256 + j2 * 16 + c] * b2v;
    }
    tmp[h] = s;
    float sd = bd[h];
    for (int j2 = 0; j2 < 16; ++j2) {
      float b2v = b2[j2];
      for (int c = 0; c < 16; ++c) sd += Wd[h * 512 + 256 + j2 * 16 + c] * b2v;
    }
    bdp[h] = sd;
  }
  __syncthreads();
  {
    int j = h >> 4, c = h & 15;
    float s1 = b1[j], s2 = b1[j];
    for (int g = 0; g < 16; ++g) {
      float w = W1[g * 16 + j];
      s1 += w * bv[g * 16 + c];
      s2 += w * tmp[g * 16 + c];
    }
    b1p[h] = s1;
    b12p[h] = s2;
  }
}

// ---------------- fused main kernel ----------------
// Swizzled LDS tile, 32 pix x 256 ch bf16: short index = p*256 + g'*8 + o,
// g' = (ch>>3) ^ (p&7), o = ch&7.  Staging writes (b128), B-frag reads
// (ds_read_b128) and epilogue writes (b64) are all bank-balanced.

__device__ __forceinline__ v8s bfrag(const short* __restrict__ S, int nt, int kt,
                                     int l15, int quad) {
  int p = nt * 16 + l15;
  int g = (kt * 4 + quad) ^ (p & 7);
  return *(const v8s*)&S[p * 256 + g * 8];
}

// K=256 GEMM phase with 1-kt-ahead register double-buffer on both operands:
// 4 a-frag L2 loads + 2 b-frag ds_reads stay in flight across the 8-MFMA
// cluster of the previous kt, hiding ~200-300cy L2 latency.
__device__ __forceinline__ void gemm8(const unsigned short* __restrict__ packA,
                                      const short* __restrict__ S,
                                      int w, int lane, int l15, int quad,
                                      v4f acc[4][2]) {
  const unsigned short* pa = packA + w * 16384 + lane * 8;  // (mi*8+kt)*512 offsets
  v8s a_cur[4], a_nxt[4], b_cur[2], b_nxt[2];
#pragma unroll
  for (int mi = 0; mi < 4; ++mi) a_cur[mi] = *(const v8s*)(pa + mi * 8 * 512);
  b_cur[0] = bfrag(S, 0, 0, l15, quad);
  b_cur[1] = bfrag(S, 1, 0, l15, quad);
#pragma unroll
  for (int kt = 0; kt < 8; ++kt) {
    if (kt < 7) {
#pragma unroll
      for (int mi = 0; mi < 4; ++mi)
        a_nxt[mi] = *(const v8s*)(pa + (mi * 8 + kt + 1) * 512);
      b_nxt[0] = bfrag(S, 0, kt + 1, l15, quad);
      b_nxt[1] = bfrag(S, 1, kt + 1, l15, quad);
    }
#pragma unroll
    for (int mi = 0; mi < 4; ++mi) {
      acc[mi][0] = __builtin_amdgcn_mfma_f32_16x16x32_bf16(a_cur[mi], b_cur[0], acc[mi][0], 0, 0, 0);
      acc[mi][1] = __builtin_amdgcn_mfma_f32_16x16x32_bf16(a_cur[mi], b_cur[1], acc[mi][1], 0, 0, 0);
    }
#pragma unroll
    for (int mi = 0; mi < 4; ++mi) a_cur[mi] = a_nxt[mi];
    b_cur[0] = b_nxt[0];
    b_cur[1] = b_nxt[1];
  }
}

__device__ __forceinline__ void epi(v4f acc[4][2], const float* __restrict__ bias,
                                    short* __restrict__ HB, int w, int l15, int quad) {
#pragma unroll
  for (int mi = 0; mi < 4; ++mi) {
    int rb = (w * 4 + mi) * 16 + quad * 4;
    float b0 = bias[rb], b1v = bias[rb + 1], b2v = bias[rb + 2], b3v = bias[rb + 3];
#pragma unroll
    for (int nt = 0; nt < 2; ++nt) {
      int p = nt * 16 + l15;
      float g0 = gelu_fast(acc[mi][nt][0] + b0);
      float g1 = gelu_fast(acc[mi][nt][1] + b1v);
      float g2 = gelu_fast(acc[mi][nt][2] + b2v);
      float g3 = gelu_fast(acc[mi][nt][3] + b3v);
      uint2 u;
      u.x = cvt_pk_bf16(g0, g1);
      u.y = cvt_pk_bf16(g2, g3);
      int g = (rb >> 3) ^ (p & 7);
      *(uint2*)&HB[p * 256 + g * 8 + (rb & 7)] = u;   // 8B-aligned b64 write
      acc[mi][nt] = (v4f){0.f, 0.f, 0.f, 0.f};
    }
  }
}

__global__ __launch_bounds__(256, 4) void fused_k(
    const float* __restrict__ x,
    const unsigned short* __restrict__ pA1, const unsigned short* __restrict__ pA12,
    const unsigned short* __restrict__ pG3,
    const float* __restrict__ b1p, const float* __restrict__ b12p,
    const float* __restrict__ bdp, float* __restrict__ out) {
  __shared__ __align__(16) short XB[PIX * 256];
  __shared__ __align__(16) short HB[PIX * 256];
  const int t = threadIdx.x;
  const int lane = t & 63, w = t >> 6;
  const int quad = lane >> 4, l15 = lane & 15;
  const int pp0 = blockIdx.x * PIX;
  const int b = pp0 >> 14, l0 = pp0 & 16383;
  const float* xb = x + ((long)b << 22) + l0;

  // Phase 1: stage X0 (32 pix x 256 ch) -> bf16 swizzled LDS.
  // Thread: one channel-octet x 4 pixels; float4 loads (16B/lane), b128 writes.
  {
    const int pq = t & 7, co = t >> 3;
    const int p0 = pq * 4;
    v4f v[8];
#pragma unroll
    for (int u = 0; u < 8; ++u)
      v[u] = *(const v4f*)(xb + (long)(co * 8 + u) * L_ + p0);
#pragma unroll
    for (int j = 0; j < 4; ++j) {
      const int p = p0 + j;
      uint4 s;
      s.x = cvt_pk_bf16(v[0][j], v[1][j]);
      s.y = cvt_pk_bf16(v[2][j], v[3][j]);
      s.z = cvt_pk_bf16(v[4][j], v[5][j]);
      s.w = cvt_pk_bf16(v[6][j], v[7][j]);
      *(uint4*)&XB[p * 256 + (co ^ (p & 7)) * 8] = s;
    }
  }

  v4f acc[4][2];
#pragma unroll
  for (int i = 0; i < 4; ++i) {
    acc[i][0] = (v4f){0.f, 0.f, 0.f, 0.f};
    acc[i][1] = (v4f){0.f, 0.f, 0.f, 0.f};
  }

  __syncthreads();

  gemm8(pA1, XB, w, lane, l15, quad, acc);      // G1: A1 @ X0
  epi(acc, b1p, HB, w, l15, quad);              // H1 = gelu(.+b1p) -> HB
  __syncthreads();
  gemm8(pA12, HB, w, lane, l15, quad, acc);     // G2: A12 @ H1
  __syncthreads();                              // all G2 reads done before overwrite
  epi(acc, b12p, HB, w, l15, quad);             // H2 = gelu(.+b12p) -> HB (in place)
  __syncthreads();

  // G3: OUT = [Wd0 | Wd2p] @ [X0; H2], K=512 (NKT=16), same 1-ahead pipeline.
  {
    const unsigned short* pg = pG3 + w * 32768 + lane * 8;  // (mi*16+kt)*512 offsets
    v8s a_cur[4], a_nxt[4], b_cur[2], b_nxt[2];
#pragma unroll
    for (int mi = 0; mi < 4; ++mi) a_cur[mi] = *(const v8s*)(pg + mi * 16 * 512);
    b_cur[0] = bfrag(XB, 0, 0, l15, quad);
    b_cur[1] = bfrag(XB, 1, 0, l15, quad);
#pragma unroll
    for (int kt = 0; kt < 16; ++kt) {
      if (kt < 15) {
        const short* Sn = (kt + 1 < 8) ? XB : HB;
        const int ktl = (kt + 1) & 7;
#pragma unroll
        for (int mi = 0; mi < 4; ++mi)
          a_nxt[mi] = *(const v8s*)(pg + (mi * 16 + kt + 1) * 512);
        b_nxt[0] = bfrag(Sn, 0, ktl, l15, quad);
        b_nxt[1] = bfrag(Sn, 1, ktl, l15, quad);
      }
#pragma unroll
      for (int mi = 0; mi < 4; ++mi) {
        acc[mi][0] = __builtin_amdgcn_mfma_f32_16x16x32_bf16(a_cur[mi], b_cur[0], acc[mi][0], 0, 0, 0);
        acc[mi][1] = __builtin_amdgcn_mfma_f32_16x16x32_bf16(a_cur[mi], b_cur[1], acc[mi][1], 0, 0, 0);
      }
#pragma unroll
      for (int mi = 0; mi < 4; ++mi) a_cur[mi] = a_nxt[mi];
      b_cur[0] = b_nxt[0];
      b_cur[1] = b_nxt[1];
    }
  }

  // Epilogue: OUT + bdp -> global fp32
  long obase = ((long)b << 22) + l0;
#pragma unroll
  for (int mi = 0; mi < 4; ++mi) {
    int rb = (w * 4 + mi) * 16 + quad * 4;
    float bb0 = bdp[rb], bb1 = bdp[rb + 1], bb2 = bdp[rb + 2], bb3 = bdp[rb + 3];
#pragma unroll
    for (int nt = 0; nt < 2; ++nt) {
      int p = nt * 16 + l15;
      out[obase + (long)(rb + 0) * L_ + p] = acc[mi][nt][0] + bb0;
      out[obase + (long)(rb + 1) * L_ + p] = acc[mi][nt][1] + bb1;
      out[obase + (long)(rb + 2) * L_ + p] = acc[mi][nt][2] + bb2;
      out[obase + (long)(rb + 3) * L_ + p] = acc[mi][nt][3] + bb3;
    }
  }
}

// ---------------- launch ----------------

extern "C" void kernel_launch(void* const* d_in, const int* in_sizes, int n_in,
                              void* d_out, int out_size, void* d_ws, size_t ws_size,
                              hipStream_t stream) {
  const float* x  = (const float*)d_in[0];
  const float* Wv = (const float*)d_in[3];
  const float* bv = (const float*)d_in[4];
  const float* W1 = (const float*)d_in[13];
  const float* b1 = (const float*)d_in[14];
  const float* W2 = (const float*)d_in[15];
  const float* b2 = (const float*)d_in[16];
  const float* Wd = (const float*)d_in[17];
  const float* bd = (const float*)d_in[18];
  float* out = (float*)d_out;

  char* ws = (char*)d_ws;
  unsigned short* pA1  = (unsigned short*)(ws + 0);        // 128 KB
  unsigned short* pA12 = (unsigned short*)(ws + 131072);   // 128 KB
  unsigned short* pG3  = (unsigned short*)(ws + 262144);   // 256 KB
  float* b1p  = (float*)(ws + 524288);
  float* b12p = (float*)(ws + 525312);
  float* bdp  = (float*)(ws + 526336);
  float* T    = (float*)(ws + 527360);                     // 256 KB

  prep_pack_k<<<1024, 256, 0, stream>>>(Wv, W1, W2, Wd, pA1, pG3, T);
  prep_a12_k <<<256, 256, 0, stream>>>(W1, T, pA12);
  prep_bias_k<<<1, 256, 0, stream>>>(Wv, bv, Wd, W1, b1, b2, bd, b1p, b12p, bdp);

  fused_k<<<4096, 256, 0, stream>>>(x, pA1, pA12, pG3, b1p, b12p, bdp, out);
}

// Round 2
// 346.882 us; speedup vs baseline: 1.1200x; 1.0815x over previous
//
#include <hip/hip_runtime.h>

// ---------------------------------------------------------------------------
// localTransformer: attention is dead code (softmax over singleton axis == 1,
// so o == v). Whole net folds to:
//   OUT = Wd0@X0 + Wd2p@gelu(A12@gelu(A1@X0 + b1p) + b12p) + bdp
// R3 restructure: single live accumulator via K=512 final GEMM
//   OUT = [Wd0 | Wd2p] @ [X0; H2]   (same accumulation order as before)
// R4: register double-buffer on a/b frags + v_cvt_pk_bf16_f32 packing.
// R5 (this round): PIX=64, 512-thread blocks (8 waves, 32 rows/wave).
//   - halves per-block weight re-fetch from L2 (2.1 GB -> 1.05 GB total)
//   - per kt step: 2 global a-loads : 8 MFMA (was 4:8) -> loads hide
//   - LDS 64KB/block, 2 blocks/CU, 16 waves/CU occupancy
// ---------------------------------------------------------------------------

typedef short v8s __attribute__((ext_vector_type(8)));   // 8 bf16 (4 VGPRs)
typedef float v4f __attribute__((ext_vector_type(4)));   // MFMA C/D, float4

#define L_   16384        // H*W
#define PIX  64           // pixels per block

__device__ __forceinline__ unsigned short bf16rne(float f) {
  union { float f; unsigned u; } v; v.f = f;
  unsigned u = v.u;
  return (unsigned short)((u + 0x7FFFu + ((u >> 16) & 1u)) >> 16);
}

// packed f32x2 -> bf16x2 (RNE), one VALU instruction. low16 = lo, high16 = hi.
__device__ __forceinline__ unsigned cvt_pk_bf16(float lo, float hi) {
  unsigned r;
  asm("v_cvt_pk_bf16_f32 %0, %1, %2" : "=v"(r) : "v"(lo), "v"(hi));
  return r;
}

// tanh-form gelu, branchless (v_exp_f32). |err vs exact erf-gelu| <= ~3e-4,
// amplified downstream by <=1e-3 total -- threshold headroom is 0.06.
__device__ __forceinline__ float gelu_fast(float x) {
  float y = 1.5957691216057308f * (x + 0.044715f * x * x * x);  // 2*0.79788456*(...)
  float e = __expf(y);
  float t = 1.0f - 2.0f / (e + 1.0f);                           // tanh(y/2*2)=tanh
  return 0.5f * x * (1.0f + t);
}

// ---------------- prep: fold + bf16-pack weights ----------------
// A-frag pack order (NKT k-tiles): idx = ((mt*NKT + kt)*64 + lane)*8 + j
//   -> element A[mt*16 + (lane&15)][kt*32 + (lane>>4)*8 + j]

// 4 segments of 65536 threads:
//  seg0: pG3[:, :256]  = pack(Wd[:, :256])              (NKT=16, kt 0..7)
//  seg1: pG3[:, 256:]  = pack(fold(Wd[:,256:], W2))     (NKT=16, kt 8..15)
//  seg2: pA1           = pack(fold(W1, Wv))             (NKT=8)
//  seg3: T[g][cp][jj][c] = sum_j2 Wv[(g*16+cp)][j2*16+c] * W2[jj*16+j2]
__global__ void prep_pack_k(const float* __restrict__ Wv, const float* __restrict__ W1,
                            const float* __restrict__ W2, const float* __restrict__ Wd,
                            unsigned short* __restrict__ pA1, unsigned short* __restrict__ pG3,
                            float* __restrict__ T) {
  int gtid = blockIdx.x * 256 + threadIdx.x;
  int seg = gtid >> 16;
  int tid = gtid & 65535;
  if (seg == 3) {
    int c = tid & 15, jj = (tid >> 4) & 15, cp = (tid >> 8) & 15, g = tid >> 12;
    float s = 0.f;
    for (int j2 = 0; j2 < 16; ++j2)
      s += Wv[(g * 16 + cp) * 256 + j2 * 16 + c] * W2[jj * 16 + j2];
    T[tid] = s;
    return;
  }
  int j = tid & 7, lane = (tid >> 3) & 63, kt = (tid >> 9) & 7, mt = tid >> 12;
  int m = mt * 16 + (lane & 15);
  int k = kt * 32 + (lane >> 4) * 8 + j;
  if (seg == 0) {
    pG3[((mt * 16 + kt) * 64 + lane) * 8 + j] = bf16rne(Wd[m * 512 + k]);
  } else if (seg == 1) {
    int jj = k >> 4, c = k & 15;
    float s = 0.f;
    for (int j2 = 0; j2 < 16; ++j2)
      s += Wd[m * 512 + 256 + j2 * 16 + c] * W2[jj * 16 + j2];
    pG3[((mt * 16 + 8 + kt) * 64 + lane) * 8 + j] = bf16rne(s);
  } else {
    int jp = m >> 4, c = m & 15;
    float s = 0.f;
    for (int g = 0; g < 16; ++g) s += W1[g * 16 + jp] * Wv[(g * 16 + c) * 256 + k];
    pA1[tid] = bf16rne(s);
  }
}

// pA12 = pack(sum_g W1 * T)  -- same summation order as 1-stage fold.
__global__ void prep_a12_k(const float* __restrict__ W1, const float* __restrict__ T,
                           unsigned short* __restrict__ dst) {
  int tid = blockIdx.x * 256 + threadIdx.x;
  int j = tid & 7, lane = (tid >> 3) & 63, kt = (tid >> 9) & 7, mt = tid >> 12;
  int m = mt * 16 + (lane & 15);
  int k = kt * 32 + (lane >> 4) * 8 + j;
  int jp = m >> 4, cp = m & 15;
  int jj = k >> 4, c = k & 15;
  float s = 0.f;
  for (int g = 0; g < 16; ++g)
    s += W1[g * 16 + jp] * T[g * 4096 + cp * 256 + jj * 16 + c];
  dst[tid] = bf16rne(s);
}

__global__ void prep_bias_k(const float* __restrict__ Wv, const float* __restrict__ bv,
                            const float* __restrict__ Wd, const float* __restrict__ W1,
                            const float* __restrict__ b1, const float* __restrict__ b2,
                            const float* __restrict__ bd,
                            float* __restrict__ b1p, float* __restrict__ b12p,
                            float* __restrict__ bdp) {
  __shared__ float tmp[256];
  int h = threadIdx.x;
  {
    int g = h >> 4, cp = h & 15;
    float s = bv[g * 16 + cp];
    for (int j2 = 0; j2 < 16; ++j2) {
      float b2v = b2[j2];
      for (int c = 0; c < 16; ++c) s += Wv[(g * 16 + cp) * 256 + j2 * 16 + c] * b2v;
    }
    tmp[h] = s;
    float sd = bd[h];
    for (int j2 = 0; j2 < 16; ++j2) {
      float b2v = b2[j2];
      for (int c = 0; c < 16; ++c) sd += Wd[h * 512 + 256 + j2 * 16 + c] * b2v;
    }
    bdp[h] = sd;
  }
  __syncthreads();
  {
    int j = h >> 4, c = h & 15;
    float s1 = b1[j], s2 = b1[j];
    for (int g = 0; g < 16; ++g) {
      float w = W1[g * 16 + j];
      s1 += w * bv[g * 16 + c];
      s2 += w * tmp[g * 16 + c];
    }
    b1p[h] = s1;
    b12p[h] = s2;
  }
}

// ---------------- fused main kernel ----------------
// Swizzled LDS tile, 64 pix x 256 ch bf16: short index = p*256 + g'*8 + o,
// g' = (ch>>3) ^ (p&7), o = ch&7.  Staging writes (b128), B-frag reads
// (ds_read_b128) and epilogue writes (b64) are all bank-balanced.

__device__ __forceinline__ v8s bfrag(const short* __restrict__ S, int nt, int kt,
                                     int l15, int quad) {
  int p = nt * 16 + l15;
  int g = (kt * 4 + quad) ^ (p & 7);
  return *(const v8s*)&S[p * 256 + g * 8];
}

// K=256 GEMM phase, wave owns 32 rows (mi in {0,1}) x 64 px (nt in 0..3).
// 1-kt-ahead register double-buffer on both operands: 2 a-frag L2 loads +
// 4 b-frag ds_reads stay in flight across the previous kt's 8-MFMA cluster.
__device__ __forceinline__ void gemm8(const unsigned short* __restrict__ packA,
                                      const short* __restrict__ S,
                                      int w, int lane, int l15, int quad,
                                      v4f acc[2][4]) {
  const unsigned short* pa = packA + w * 2 * 8 * 512 + lane * 8;  // mt = w*2+mi
  v8s a_cur[2], a_nxt[2], b_cur[4], b_nxt[4];
#pragma unroll
  for (int mi = 0; mi < 2; ++mi) a_cur[mi] = *(const v8s*)(pa + mi * 8 * 512);
#pragma unroll
  for (int nt = 0; nt < 4; ++nt) b_cur[nt] = bfrag(S, nt, 0, l15, quad);
#pragma unroll
  for (int kt = 0; kt < 8; ++kt) {
    if (kt < 7) {
#pragma unroll
      for (int mi = 0; mi < 2; ++mi)
        a_nxt[mi] = *(const v8s*)(pa + (mi * 8 + kt + 1) * 512);
#pragma unroll
      for (int nt = 0; nt < 4; ++nt) b_nxt[nt] = bfrag(S, nt, kt + 1, l15, quad);
    }
#pragma unroll
    for (int mi = 0; mi < 2; ++mi)
#pragma unroll
      for (int nt = 0; nt < 4; ++nt)
        acc[mi][nt] = __builtin_amdgcn_mfma_f32_16x16x32_bf16(a_cur[mi], b_cur[nt], acc[mi][nt], 0, 0, 0);
#pragma unroll
    for (int mi = 0; mi < 2; ++mi) a_cur[mi] = a_nxt[mi];
#pragma unroll
    for (int nt = 0; nt < 4; ++nt) b_cur[nt] = b_nxt[nt];
  }
}

__device__ __forceinline__ void epi(v4f acc[2][4], const float* __restrict__ bias,
                                    short* __restrict__ HB, int w, int l15, int quad) {
#pragma unroll
  for (int mi = 0; mi < 2; ++mi) {
    int rb = (w * 2 + mi) * 16 + quad * 4;
    float b0 = bias[rb], b1v = bias[rb + 1], b2v = bias[rb + 2], b3v = bias[rb + 3];
#pragma unroll
    for (int nt = 0; nt < 4; ++nt) {
      int p = nt * 16 + l15;
      float g0 = gelu_fast(acc[mi][nt][0] + b0);
      float g1 = gelu_fast(acc[mi][nt][1] + b1v);
      float g2 = gelu_fast(acc[mi][nt][2] + b2v);
      float g3 = gelu_fast(acc[mi][nt][3] + b3v);
      uint2 u;
      u.x = cvt_pk_bf16(g0, g1);
      u.y = cvt_pk_bf16(g2, g3);
      int g = (rb >> 3) ^ (p & 7);
      *(uint2*)&HB[p * 256 + g * 8 + (rb & 7)] = u;   // 8B-aligned b64 write
      acc[mi][nt] = (v4f){0.f, 0.f, 0.f, 0.f};
    }
  }
}

__global__ __launch_bounds__(512, 4) void fused_k(
    const float* __restrict__ x,
    const unsigned short* __restrict__ pA1, const unsigned short* __restrict__ pA12,
    const unsigned short* __restrict__ pG3,
    const float* __restrict__ b1p, const float* __restrict__ b12p,
    const float* __restrict__ bdp, float* __restrict__ out) {
  __shared__ __align__(16) short XB[PIX * 256];
  __shared__ __align__(16) short HB[PIX * 256];
  const int t = threadIdx.x;
  const int lane = t & 63, w = t >> 6;                 // 8 waves
  const int quad = lane >> 4, l15 = lane & 15;
  const int pp0 = blockIdx.x * PIX;
  const int b = pp0 >> 14, l0 = pp0 & 16383;
  const float* xb = x + ((long)b << 22) + l0;

  // Phase 1: stage X0 (64 pix x 256 ch) -> bf16 swizzled LDS.
  // Thread: one channel-octet x 4 pixels; float4 loads (16B/lane), b128 writes.
  {
    const int pq = t & 15, co = t >> 4;                // co 0..31, pq 0..15
    const int p0 = pq * 4;
    v4f v[8];
#pragma unroll
    for (int u = 0; u < 8; ++u)
      v[u] = *(const v4f*)(xb + (long)(co * 8 + u) * L_ + p0);
#pragma unroll
    for (int j = 0; j < 4; ++j) {
      const int p = p0 + j;
      uint4 s;
      s.x = cvt_pk_bf16(v[0][j], v[1][j]);
      s.y = cvt_pk_bf16(v[2][j], v[3][j]);
      s.z = cvt_pk_bf16(v[4][j], v[5][j]);
      s.w = cvt_pk_bf16(v[6][j], v[7][j]);
      *(uint4*)&XB[p * 256 + ((co ^ (p & 7)) * 8)];
      *(uint4*)&XB[p * 256 + ((co ^ (p & 7)) * 8)] = s;
    }
  }

  v4f acc[2][4];
#pragma unroll
  for (int i = 0; i < 2; ++i)
#pragma unroll
    for (int n = 0; n < 4; ++n) acc[i][n] = (v4f){0.f, 0.f, 0.f, 0.f};

  __syncthreads();

  gemm8(pA1, XB, w, lane, l15, quad, acc);      // G1: A1 @ X0
  epi(acc, b1p, HB, w, l15, quad);              // H1 = gelu(.+b1p) -> HB
  __syncthreads();
  gemm8(pA12, HB, w, lane, l15, quad, acc);     // G2: A12 @ H1
  __syncthreads();                              // all G2 reads done before overwrite
  epi(acc, b12p, HB, w, l15, quad);             // H2 = gelu(.+b12p) -> HB (in place)
  __syncthreads();

  // G3: OUT = [Wd0 | Wd2p] @ [X0; H2], K=512 (NKT=16), same 1-ahead pipeline.
  {
    const unsigned short* pg = pG3 + w * 2 * 16 * 512 + lane * 8;  // mt = w*2+mi
    v8s a_cur[2], a_nxt[2], b_cur[4], b_nxt[4];
#pragma unroll
    for (int mi = 0; mi < 2; ++mi) a_cur[mi] = *(const v8s*)(pg + mi * 16 * 512);
#pragma unroll
    for (int nt = 0; nt < 4; ++nt) b_cur[nt] = bfrag(XB, nt, 0, l15, quad);
#pragma unroll
    for (int kt = 0; kt < 16; ++kt) {
      if (kt < 15) {
        const short* Sn = (kt + 1 < 8) ? XB : HB;
        const int ktl = (kt + 1) & 7;
#pragma unroll
        for (int mi = 0; mi < 2; ++mi)
          a_nxt[mi] = *(const v8s*)(pg + (mi * 16 + kt + 1) * 512);
#pragma unroll
        for (int nt = 0; nt < 4; ++nt) b_nxt[nt] = bfrag(Sn, nt, ktl, l15, quad);
      }
#pragma unroll
      for (int mi = 0; mi < 2; ++mi)
#pragma unroll
        for (int nt = 0; nt < 4; ++nt)
          acc[mi][nt] = __builtin_amdgcn_mfma_f32_16x16x32_bf16(a_cur[mi], b_cur[nt], acc[mi][nt], 0, 0, 0);
#pragma unroll
      for (int mi = 0; mi < 2; ++mi) a_cur[mi] = a_nxt[mi];
#pragma unroll
      for (int nt = 0; nt < 4; ++nt) b_cur[nt] = b_nxt[nt];
    }
  }

  // Epilogue: OUT + bdp -> global fp32
  long obase = ((long)b << 22) + l0;
#pragma unroll
  for (int mi = 0; mi < 2; ++mi) {
    int rb = (w * 2 + mi) * 16 + quad * 4;
    float bb0 = bdp[rb], bb1 = bdp[rb + 1], bb2 = bdp[rb + 2], bb3 = bdp[rb + 3];
#pragma unroll
    for (int nt = 0; nt < 4; ++nt) {
      int p = nt * 16 + l15;
      out[obase + (long)(rb + 0) * L_ + p] = acc[mi][nt][0] + bb0;
      out[obase + (long)(rb + 1) * L_ + p] = acc[mi][nt][1] + bb1;
      out[obase + (long)(rb + 2) * L_ + p] = acc[mi][nt][2] + bb2;
      out[obase + (long)(rb + 3) * L_ + p] = acc[mi][nt][3] + bb3;
    }
  }
}

// ---------------- launch ----------------

extern "C" void kernel_launch(void* const* d_in, const int* in_sizes, int n_in,
                              void* d_out, int out_size, void* d_ws, size_t ws_size,
                              hipStream_t stream) {
  const float* x  = (const float*)d_in[0];
  const float* Wv = (const float*)d_in[3];
  const float* bv = (const float*)d_in[4];
  const float* W1 = (const float*)d_in[13];
  const float* b1 = (const float*)d_in[14];
  const float* W2 = (const float*)d_in[15];
  const float* b2 = (const float*)d_in[16];
  const float* Wd = (const float*)d_in[17];
  const float* bd = (const float*)d_in[18];
  float* out = (float*)d_out;

  char* ws = (char*)d_ws;
  unsigned short* pA1  = (unsigned short*)(ws + 0);        // 128 KB
  unsigned short* pA12 = (unsigned short*)(ws + 131072);   // 128 KB
  unsigned short* pG3  = (unsigned short*)(ws + 262144);   // 256 KB
  float* b1p  = (float*)(ws + 524288);
  float* b12p = (float*)(ws + 525312);
  float* bdp  = (float*)(ws + 526336);
  float* T    = (float*)(ws + 527360);                     // 256 KB

  prep_pack_k<<<1024, 256, 0, stream>>>(Wv, W1, W2, Wd, pA1, pG3, T);
  prep_a12_k <<<256, 256, 0, stream>>>(W1, T, pA12);
  prep_bias_k<<<1, 256, 0, stream>>>(Wv, bv, Wd, W1, b1, b2, bd, b1p, b12p, bdp);

  fused_k<<<2048, 512, 0, stream>>>(x, pA1, pA12, pG3, b1p, b12p, bdp, out);
}